// Round 2
// baseline (709.466 us; speedup 1.0000x reference)
//
#include <hip/hip_runtime.h>
#include <stdint.h>

#define GLOBAL_AS __attribute__((address_space(1)))
#define LDS_AS    __attribute__((address_space(3)))

typedef __attribute__((ext_vector_type(8))) short bf16x8;   // 8 bf16 = 4 VGPRs
typedef __attribute__((ext_vector_type(4))) float f32x4;

#define B_DIM 2048
#define D_DIM 4096
#define Q_DIM 1024
#define EPSF  1e-8f

__device__ __forceinline__ unsigned short f2bf(float f) {
  union { float f; unsigned int u; } v; v.f = f;
  unsigned int u = v.u;
  u += 0x7FFFu + ((u >> 16) & 1u);   // round-to-nearest-even
  return (unsigned short)(u >> 16);
}

// ---------------- K0: f32 -> bf16 conversion (x, W_phi, W_dde) ----------------
#define NX4    2097152u   // 2048*4096/4
#define NWPHI4 4194304u   // 4096*4096/4
#define NWDDE4 1048576u   // 1024*4096/4

__global__ __launch_bounds__(256) void k_convert(
    const float* __restrict__ x, const float* __restrict__ wphi,
    const float* __restrict__ wdde,
    unsigned short* __restrict__ xb, unsigned short* __restrict__ wphib,
    unsigned short* __restrict__ wddeb, float* __restrict__ drift) {
  unsigned int idx = blockIdx.x * 256u + threadIdx.x;
  if (idx == 0) *drift = 0.0f;
  const float4* s; ushort4* d; unsigned int local;
  if (idx < NX4)              { s = (const float4*)x;    d = (ushort4*)xb;    local = idx; }
  else if (idx < NX4 + NWPHI4){ s = (const float4*)wphi; d = (ushort4*)wphib; local = idx - NX4; }
  else                        { s = (const float4*)wdde; d = (ushort4*)wddeb; local = idx - (NX4 + NWPHI4); }
  float4 v = s[local];
  d[local] = make_ushort4(f2bf(v.x), f2bf(v.y), f2bf(v.z), f2bf(v.w));
}

// Swizzle: LDS chunk c (16B) holds global k-chunk (c&7)^((c>>3)&7) of row c>>3.
// Fragment read of k-chunk kc, row r -> LDS chunk r*8 + (kc ^ (r&7)).
// Bank math: row stride 64 el = 32 dwords -> addr mod 32 = (kc^(lm&7))*4 -> 8
// distinct bank-quads over 16 lanes -> 2-way aliasing = free (m136).

// ---------------- K1 (fallback, ws<110MB): GEMM1 + quaternion epilogue ----------------
// 128x128 tile, BK=64, swizzled LDS; 4 waves 2x2, each 64x64 (4x4 MFMA tiles).
__global__ __launch_bounds__(256) void k_gemm1(
    const unsigned short* __restrict__ A, const unsigned short* __restrict__ Bm,
    const float* __restrict__ bphi, const float* __restrict__ state,
    float* __restrict__ nsf /* d_out as [2048,4096] f32 next_state */,
    unsigned short* __restrict__ nsb /* ws: next_state bf16 */,
    float* __restrict__ drift) {
  __shared__ __align__(16) unsigned short sAB[2 * 128 * 64];  // 32 KB
  const int t = threadIdx.x;
  const int lane = t & 63;
  const int w = t >> 6;
  const int bn = blockIdx.x;   // 0..31
  const int bm = blockIdx.y;   // 0..15
  const int rowA0 = bm * 128;
  const int rowB0 = bn * 128;

  const unsigned short* gA[4]; const unsigned short* gB[4];
  unsigned short *lA[4], *lB[4];
#pragma unroll
  for (int p = 0; p < 4; ++p) {
    const int c = t + p * 256;
    const int row = c >> 3;
    const int kcg = (c & 7) ^ (row & 7);           // swizzled global k-chunk
    gA[p] = A  + (size_t)(rowA0 + row) * D_DIM + kcg * 8;
    gB[p] = Bm + (size_t)(rowB0 + row) * D_DIM + kcg * 8;
    lA[p] = &sAB[c * 8];
    lB[p] = &sAB[8192 + c * 8];
  }

  f32x4 acc[4][4] = {};
  const int lm = lane & 15;
  const int lq = lane >> 4;
  const int mbase = (w >> 1) * 64;
  const int nbase = (w & 1) * 64;
  const int rsw = lm & 7;

  for (int k0 = 0; k0 < D_DIM; k0 += 64) {
#pragma unroll
    for (int p = 0; p < 4; ++p) {
      __builtin_amdgcn_global_load_lds((const GLOBAL_AS unsigned int*)(gA[p] + k0), (LDS_AS unsigned int*)lA[p], 16, 0, 0);
      __builtin_amdgcn_global_load_lds((const GLOBAL_AS unsigned int*)(gB[p] + k0), (LDS_AS unsigned int*)lB[p], 16, 0, 0);
    }
    __syncthreads();
#pragma unroll
    for (int ks = 0; ks < 2; ++ks) {
      const int kc = ks * 4 + lq;
      const int csw = (kc ^ rsw) * 8;
      bf16x8 af[4], bfr[4];
#pragma unroll
      for (int i = 0; i < 4; ++i)
        af[i] = *(const bf16x8*)&sAB[(mbase + i * 16 + lm) * 64 + csw];
#pragma unroll
      for (int j = 0; j < 4; ++j)
        bfr[j] = *(const bf16x8*)&sAB[8192 + (nbase + j * 16 + lm) * 64 + csw];
#pragma unroll
      for (int i = 0; i < 4; ++i)
#pragma unroll
        for (int j = 0; j < 4; ++j)
          acc[i][j] = __builtin_amdgcn_mfma_f32_16x16x32_bf16(af[i], bfr[j], acc[i][j], 0, 0, 0);
    }
    __syncthreads();
  }

  // C/D layout: col = lane&15, row = (lane>>4)*4 + reg  [m89-verified]
  float* cscr = ((float*)sAB) + w * 1024;
  float driftLocal = 0.0f;
  const int colBase = rowB0 + nbase;
  const int qBase = colBase >> 2;
#pragma unroll
  for (int i = 0; i < 4; ++i) {
    __syncthreads();
#pragma unroll
    for (int j = 0; j < 4; ++j)
#pragma unroll
      for (int r = 0; r < 4; ++r)
        cscr[(lq * 4 + r) * 64 + j * 16 + lm] = acc[i][j][r];
    __syncthreads();
#pragma unroll
    for (int s = 0; s < 4; ++s) {
      const int qlin = s * 64 + lane;
      const int lrow = qlin >> 4;
      const int qc = qlin & 15;
      float4 vq = *(const float4*)&cscr[lrow * 64 + qc * 4];
      float4 bq = ((const float4*)bphi)[qBase + qc];
      float vx = vq.y + bq.y, vy = vq.z + bq.z, vz = vq.w + bq.w;
      float th = sqrtf(vx * vx + vy * vy + vz * vz) + EPSF;
      float st = sinf(th), ct = cosf(th);
      float sc = st / th;
      float rw = ct, rx = vx * sc, ry = vy * sc, rz = vz * sc;
      const int grow = rowA0 + mbase + i * 16 + lrow;
      const size_t qgi = (size_t)grow * Q_DIM + (qBase + qc);
      float4 sq = ((const float4*)state)[qgi];
      float aw = sq.x, ax = sq.y, ay = sq.z, az = sq.w;
      float nw = aw * rw - ax * rx - ay * ry - az * rz;
      float nx = aw * rx + rw * ax + (ay * rz - az * ry);
      float ny = aw * ry + rw * ay + (az * rx - ax * rz);
      float nz = aw * rz + rw * az + (ax * ry - ay * rx);
      float nrm = sqrtf(nw * nw + nx * nx + ny * ny + nz * nz);
      float invn = 1.0f / (nrm + EPSF);
      nw *= invn; nx *= invn; ny *= invn; nz *= invn;
      float n2 = sqrtf(nw * nw + nx * nx + ny * ny + nz * nz);
      driftLocal += fabsf(n2 - 1.0f);
      float4 o; o.x = nw; o.y = nx; o.z = ny; o.w = nz;
      ((float4*)nsf)[qgi] = o;
      ((ushort4*)nsb)[qgi] = make_ushort4(f2bf(nw), f2bf(nx), f2bf(ny), f2bf(nz));
    }
  }
#pragma unroll
  for (int off = 32; off > 0; off >>= 1) driftLocal += __shfl_down(driftLocal, off);
  if (lane == 0) atomicAdd(drift, driftLocal);
}

// ---------------- K1s (split path): GEMM1 split-K=2, partial stores ----------------
// grid (32,16,2) = 1024 blocks -> 4/CU resident (VGPR 96, LDS 32KB allow 5).
// sk=0 -> p0 (= d_out, dead until k_quat), sk=1 -> p1 (ws). Row-major f32 [2048][4096].
__global__ __launch_bounds__(256) void k_gemm1s(
    const unsigned short* __restrict__ A, const unsigned short* __restrict__ Bm,
    float* __restrict__ p0, float* __restrict__ p1) {
  __shared__ __align__(16) unsigned short sAB[2 * 128 * 64];  // 32 KB
  const int t = threadIdx.x;
  const int lane = t & 63;
  const int w = t >> 6;
  const int bn = blockIdx.x;   // 0..31
  const int bm = blockIdx.y;   // 0..15
  const int sk = blockIdx.z;   // 0..1
  const int rowA0 = bm * 128;
  const int rowB0 = bn * 128;
  const int kbeg = sk * 2048;

  const unsigned short* gA[4]; const unsigned short* gB[4];
  unsigned short *lA[4], *lB[4];
#pragma unroll
  for (int p = 0; p < 4; ++p) {
    const int c = t + p * 256;
    const int row = c >> 3;
    const int kcg = (c & 7) ^ (row & 7);
    gA[p] = A  + (size_t)(rowA0 + row) * D_DIM + kbeg + kcg * 8;
    gB[p] = Bm + (size_t)(rowB0 + row) * D_DIM + kbeg + kcg * 8;
    lA[p] = &sAB[c * 8];
    lB[p] = &sAB[8192 + c * 8];
  }

  f32x4 acc[4][4] = {};
  const int lm = lane & 15;
  const int lq = lane >> 4;
  const int mbase = (w >> 1) * 64;
  const int nbase = (w & 1) * 64;
  const int rsw = lm & 7;

  for (int k0 = 0; k0 < 2048; k0 += 64) {
#pragma unroll
    for (int p = 0; p < 4; ++p) {
      __builtin_amdgcn_global_load_lds((const GLOBAL_AS unsigned int*)(gA[p] + k0), (LDS_AS unsigned int*)lA[p], 16, 0, 0);
      __builtin_amdgcn_global_load_lds((const GLOBAL_AS unsigned int*)(gB[p] + k0), (LDS_AS unsigned int*)lB[p], 16, 0, 0);
    }
    __syncthreads();
#pragma unroll
    for (int ks = 0; ks < 2; ++ks) {
      const int kc = ks * 4 + lq;
      const int csw = (kc ^ rsw) * 8;
      bf16x8 af[4], bfr[4];
#pragma unroll
      for (int i = 0; i < 4; ++i)
        af[i] = *(const bf16x8*)&sAB[(mbase + i * 16 + lm) * 64 + csw];
#pragma unroll
      for (int j = 0; j < 4; ++j)
        bfr[j] = *(const bf16x8*)&sAB[8192 + (nbase + j * 16 + lm) * 64 + csw];
#pragma unroll
      for (int i = 0; i < 4; ++i)
#pragma unroll
        for (int j = 0; j < 4; ++j)
          acc[i][j] = __builtin_amdgcn_mfma_f32_16x16x32_bf16(af[i], bfr[j], acc[i][j], 0, 0, 0);
    }
    __syncthreads();
  }

  // C/D layout: col = lane&15, row = (lane>>4)*4 + reg  [m89-verified]
  float* dst = sk ? p1 : p0;
#pragma unroll
  for (int i = 0; i < 4; ++i) {
    const int grow0 = rowA0 + mbase + i * 16 + lq * 4;
#pragma unroll
    for (int j = 0; j < 4; ++j) {
      const int gcol = rowB0 + nbase + j * 16 + lm;
#pragma unroll
      for (int r = 0; r < 4; ++r)
        dst[(size_t)(grow0 + r) * D_DIM + gcol] = acc[i][j][r];
    }
  }
}

// ---------------- K1e (split path): reduce partials + quaternion epilogue ----------------
// One thread per quaternion (2M). Reads p0(out)+p1+bphi+state; writes nsf (out,
// in place) + nsb; wave-reduced drift atomicAdd. ~144MB traffic ≈ 23 us.
__global__ __launch_bounds__(256) void k_quat(
    const float* __restrict__ p1, const float* __restrict__ bphi,
    const float* __restrict__ state, float* __restrict__ out,
    unsigned short* __restrict__ nsb, float* __restrict__ drift) {
  const unsigned int idx = blockIdx.x * 256u + threadIdx.x;  // 0..2097151
  const unsigned int qc = idx & 1023u;                        // quaternion col
  float4 v0 = ((const float4*)out)[idx];
  float4 v1 = ((const float4*)p1)[idx];
  float4 bq = ((const float4*)bphi)[qc];
  float vx = v0.y + v1.y + bq.y;
  float vy = v0.z + v1.z + bq.z;
  float vz = v0.w + v1.w + bq.w;
  float th = sqrtf(vx * vx + vy * vy + vz * vz) + EPSF;
  float st = sinf(th), ct = cosf(th);
  float sc = st / th;
  float rw = ct, rx = vx * sc, ry = vy * sc, rz = vz * sc;
  float4 sq = ((const float4*)state)[idx];
  float aw = sq.x, ax = sq.y, ay = sq.z, az = sq.w;
  float nw = aw * rw - ax * rx - ay * ry - az * rz;
  float nx = aw * rx + rw * ax + (ay * rz - az * ry);
  float ny = aw * ry + rw * ay + (az * rx - ax * rz);
  float nz = aw * rz + rw * az + (ax * ry - ay * rx);
  float nrm = sqrtf(nw * nw + nx * nx + ny * ny + nz * nz);
  float invn = 1.0f / (nrm + EPSF);
  nw *= invn; nx *= invn; ny *= invn; nz *= invn;
  float n2 = sqrtf(nw * nw + nx * nx + ny * ny + nz * nz);
  float driftLocal = fabsf(n2 - 1.0f);
  float4 o; o.x = nw; o.y = nx; o.z = ny; o.w = nz;
  ((float4*)out)[idx] = o;
  ((ushort4*)nsb)[idx] = make_ushort4(f2bf(nw), f2bf(nx), f2bf(ny), f2bf(nz));
#pragma unroll
  for (int off = 32; off > 0; off >>= 1) driftLocal += __shfl_down(driftLocal, off);
  if ((threadIdx.x & 63) == 0) atomicAdd(drift, driftLocal);
}

// ---------------- K2: GEMM2 (logits = ns * W_dde^T), split-K=4 ----------------
__global__ __launch_bounds__(256) void k_gemm2(
    const unsigned short* __restrict__ A /* ns bf16 [2048,4096] */,
    const unsigned short* __restrict__ Bm /* W_dde bf16 [1024,4096] */,
    float* __restrict__ part /* ws: [4][2048][1024] f32 partial logits */) {
  __shared__ __align__(16) unsigned short sAB[2 * 128 * 64];  // 32 KB
  const int t = threadIdx.x;
  const int lane = t & 63;
  const int w = t >> 6;
  const int bn = blockIdx.x;   // 0..7  (q tiles)
  const int bm = blockIdx.y;   // 0..15 (row tiles)
  const int sk = blockIdx.z;   // 0..3  (k split)
  const int rowA0 = bm * 128;
  const int rowB0 = bn * 128;
  const int kbeg = sk * 1024;

  const unsigned short* gA[4]; const unsigned short* gB[4];
  unsigned short *lA[4], *lB[4];
#pragma unroll
  for (int p = 0; p < 4; ++p) {
    const int c = t + p * 256;
    const int row = c >> 3;
    const int kcg = (c & 7) ^ (row & 7);
    gA[p] = A  + (size_t)(rowA0 + row) * D_DIM + kbeg + kcg * 8;
    gB[p] = Bm + (size_t)(rowB0 + row) * D_DIM + kbeg + kcg * 8;
    lA[p] = &sAB[c * 8];
    lB[p] = &sAB[8192 + c * 8];
  }

  f32x4 acc[4][4] = {};
  const int lm = lane & 15;
  const int lq = lane >> 4;
  const int mbase = (w >> 1) * 64;
  const int nbase = (w & 1) * 64;
  const int rsw = lm & 7;

  for (int k0 = 0; k0 < 1024; k0 += 64) {
#pragma unroll
    for (int p = 0; p < 4; ++p) {
      __builtin_amdgcn_global_load_lds((const GLOBAL_AS unsigned int*)(gA[p] + k0), (LDS_AS unsigned int*)lA[p], 16, 0, 0);
      __builtin_amdgcn_global_load_lds((const GLOBAL_AS unsigned int*)(gB[p] + k0), (LDS_AS unsigned int*)lB[p], 16, 0, 0);
    }
    __syncthreads();
#pragma unroll
    for (int ks = 0; ks < 2; ++ks) {
      const int kc = ks * 4 + lq;
      const int csw = (kc ^ rsw) * 8;
      bf16x8 af[4], bfr[4];
#pragma unroll
      for (int i = 0; i < 4; ++i)
        af[i] = *(const bf16x8*)&sAB[(mbase + i * 16 + lm) * 64 + csw];
#pragma unroll
      for (int j = 0; j < 4; ++j)
        bfr[j] = *(const bf16x8*)&sAB[8192 + (nbase + j * 16 + lm) * 64 + csw];
#pragma unroll
      for (int i = 0; i < 4; ++i)
#pragma unroll
        for (int j = 0; j < 4; ++j)
          acc[i][j] = __builtin_amdgcn_mfma_f32_16x16x32_bf16(af[i], bfr[j], acc[i][j], 0, 0, 0);
    }
    __syncthreads();
  }

  float* pS = part + (size_t)sk * (2048u * 1024u);
#pragma unroll
  for (int i = 0; i < 4; ++i) {
    const int grow0 = rowA0 + mbase + i * 16 + lq * 4;
#pragma unroll
    for (int j = 0; j < 4; ++j) {
      const int gcol = rowB0 + nbase + j * 16 + lm;
#pragma unroll
      for (int r = 0; r < 4; ++r)
        pS[(size_t)(grow0 + r) * Q_DIM + gcol] = acc[i][j][r];
    }
  }
}

// ---------------- K3: reduce partials + gate + blend (+eta) ----------------
__global__ __launch_bounds__(256) void k_blend(
    const float* __restrict__ part, const float* __restrict__ bdde,
    const float* __restrict__ state, float* __restrict__ out,
    const float* __restrict__ drift, int eta_idx) {
  const unsigned int idx = blockIdx.x * 256u + threadIdx.x;  // 0..2097151
  const unsigned int q = idx & 1023u;
  float z = part[idx] + part[idx + 2097152u] + part[idx + 4194304u] +
            part[idx + 6291456u] + bdde[q];
  float gate = 1.0f / (1.0f + expf(-z));
  float4 sq = ((const float4*)state)[idx];
  float4 nq = ((const float4*)out)[idx];   // ns f32 written by k_gemm1/k_quat
  float4 f;
  f.x = sq.x + gate * (nq.x - sq.x);
  f.y = sq.y + gate * (nq.y - sq.y);
  f.z = sq.z + gate * (nq.z - sq.z);
  f.w = sq.w + gate * (nq.w - sq.w);
  ((float4*)out)[idx] = f;                 // in-place: same thread read->write
  if (idx == 0) out[eta_idx] = *drift * (1.0f / 2097152.0f);  // mean over B*Q
}

extern "C" void kernel_launch(void* const* d_in, const int* in_sizes, int n_in,
                              void* d_out, int out_size, void* d_ws, size_t ws_size,
                              hipStream_t stream) {
  const float* x     = (const float*)d_in[0];
  const float* state = (const float*)d_in[1];
  const float* wphi  = (const float*)d_in[2];
  const float* bphi  = (const float*)d_in[3];
  const float* wdde  = (const float*)d_in[4];
  const float* bdde  = (const float*)d_in[5];
  float* out = (float*)d_out;
  char* ws = (char*)d_ws;

  if (ws_size >= 109051908ull) {
    // Split path. ws: [0,16M) xb | [16M,48M) wphib | [48M,80M) p1 |
    //                 [80M,88M) wddeb | [88M,104M) nsb | [104M,+4) drift
    // gemm2 partials reuse [0,33.5M) (xb/wphib dead after k_gemm1s/k_quat).
    unsigned short* xb    = (unsigned short*)(ws);
    unsigned short* wphib = (unsigned short*)(ws + 16777216);
    float*          p1    = (float*)(ws + 50331648);
    unsigned short* wddeb = (unsigned short*)(ws + 83886080);
    unsigned short* nsb   = (unsigned short*)(ws + 92274688);
    float*          drift = (float*)(ws + 109051904);
    float*          part  = (float*)(ws);

    k_convert<<<28672, 256, 0, stream>>>(x, wphi, wdde, xb, wphib, wddeb, drift);
    dim3 g1(32, 16, 2);
    k_gemm1s<<<g1, 256, 0, stream>>>(xb, wphib, out, p1);
    k_quat<<<8192, 256, 0, stream>>>(p1, bphi, state, out, nsb, drift);
    dim3 g2(8, 16, 4);
    k_gemm2<<<g2, 256, 0, stream>>>(nsb, wddeb, part);
    k_blend<<<8192, 256, 0, stream>>>(part, bdde, state, out, drift, out_size - 1);
  } else {
    // Fallback: exact R1 path (proven 321 us), ws peak 72MB+4.
    unsigned short* xb    = (unsigned short*)(ws);
    unsigned short* wphib = (unsigned short*)(ws + 16777216);
    unsigned short* wddeb = (unsigned short*)(ws + 50331648);
    unsigned short* nsb   = (unsigned short*)(ws + 58720256);
    float*          drift = (float*)(ws + 75497472);
    float*          part  = (float*)(ws);

    k_convert<<<28672, 256, 0, stream>>>(x, wphi, wdde, xb, wphib, wddeb, drift);
    dim3 g1(32, 16);
    k_gemm1<<<g1, 256, 0, stream>>>(xb, wphib, bphi, state, out, nsb, drift);
    dim3 g2(8, 16, 4);
    k_gemm2<<<g2, 256, 0, stream>>>(nsb, wddeb, part);
    k_blend<<<8192, 256, 0, stream>>>(part, bdde, state, out, drift, out_size - 1);
  }
}

// Round 3
// 329.120 us; speedup vs baseline: 2.1556x; 2.1556x over previous
//
#include <hip/hip_runtime.h>
#include <stdint.h>

#define GLOBAL_AS __attribute__((address_space(1)))
#define LDS_AS    __attribute__((address_space(3)))

typedef __attribute__((ext_vector_type(8))) short bf16x8;   // 8 bf16 = 4 VGPRs
typedef __attribute__((ext_vector_type(4))) float f32x4;

#define B_DIM 2048
#define D_DIM 4096
#define Q_DIM 1024
#define EPSF  1e-8f

__device__ __forceinline__ unsigned short f2bf(float f) {
  union { float f; unsigned int u; } v; v.f = f;
  unsigned int u = v.u;
  u += 0x7FFFu + ((u >> 16) & 1u);   // round-to-nearest-even
  return (unsigned short)(u >> 16);
}

// ---------------- K0: f32 -> bf16 conversion (x, W_phi, W_dde) ----------------
#define NX4    2097152u   // 2048*4096/4
#define NWPHI4 4194304u   // 4096*4096/4
#define NWDDE4 1048576u   // 1024*4096/4

__global__ __launch_bounds__(256) void k_convert(
    const float* __restrict__ x, const float* __restrict__ wphi,
    const float* __restrict__ wdde,
    unsigned short* __restrict__ xb, unsigned short* __restrict__ wphib,
    unsigned short* __restrict__ wddeb, float* __restrict__ drift) {
  unsigned int idx = blockIdx.x * 256u + threadIdx.x;
  if (idx == 0) *drift = 0.0f;
  const float4* s; ushort4* d; unsigned int local;
  if (idx < NX4)              { s = (const float4*)x;    d = (ushort4*)xb;    local = idx; }
  else if (idx < NX4 + NWPHI4){ s = (const float4*)wphi; d = (ushort4*)wphib; local = idx - NX4; }
  else                        { s = (const float4*)wdde; d = (ushort4*)wddeb; local = idx - (NX4 + NWPHI4); }
  float4 v = s[local];
  d[local] = make_ushort4(f2bf(v.x), f2bf(v.y), f2bf(v.z), f2bf(v.w));
}

// Swizzle: LDS chunk c (16B) holds global k-chunk (c&7)^((c>>3)&7) of row c>>3.
// Fragment read of k-chunk kc, row r -> LDS chunk r*8 + (kc ^ (r&7)).
// Bank math: row stride 64 el = 32 dwords -> addr mod 32 = (kc^(lm&7))*4 -> 8
// distinct bank-quads over 16 lanes -> 2-way aliasing = free (m136).

// ---------------- K1 (fallback, ws<110MB): GEMM1 + quaternion epilogue ----------------
__global__ __launch_bounds__(256) void k_gemm1(
    const unsigned short* __restrict__ A, const unsigned short* __restrict__ Bm,
    const float* __restrict__ bphi, const float* __restrict__ state,
    float* __restrict__ nsf, unsigned short* __restrict__ nsb,
    float* __restrict__ drift) {
  __shared__ __align__(16) unsigned short sAB[2 * 128 * 64];  // 32 KB
  const int t = threadIdx.x;
  const int lane = t & 63;
  const int w = t >> 6;
  const int bn = blockIdx.x;
  const int bm = blockIdx.y;
  const int rowA0 = bm * 128;
  const int rowB0 = bn * 128;

  const unsigned short* gA[4]; const unsigned short* gB[4];
  unsigned short *lA[4], *lB[4];
#pragma unroll
  for (int p = 0; p < 4; ++p) {
    const int c = t + p * 256;
    const int row = c >> 3;
    const int kcg = (c & 7) ^ (row & 7);
    gA[p] = A  + (size_t)(rowA0 + row) * D_DIM + kcg * 8;
    gB[p] = Bm + (size_t)(rowB0 + row) * D_DIM + kcg * 8;
    lA[p] = &sAB[c * 8];
    lB[p] = &sAB[8192 + c * 8];
  }

  f32x4 acc[4][4] = {};
  const int lm = lane & 15;
  const int lq = lane >> 4;
  const int mbase = (w >> 1) * 64;
  const int nbase = (w & 1) * 64;
  const int rsw = lm & 7;

  for (int k0 = 0; k0 < D_DIM; k0 += 64) {
#pragma unroll
    for (int p = 0; p < 4; ++p) {
      __builtin_amdgcn_global_load_lds((const GLOBAL_AS unsigned int*)(gA[p] + k0), (LDS_AS unsigned int*)lA[p], 16, 0, 0);
      __builtin_amdgcn_global_load_lds((const GLOBAL_AS unsigned int*)(gB[p] + k0), (LDS_AS unsigned int*)lB[p], 16, 0, 0);
    }
    __syncthreads();
#pragma unroll
    for (int ks = 0; ks < 2; ++ks) {
      const int kc = ks * 4 + lq;
      const int csw = (kc ^ rsw) * 8;
      bf16x8 af[4], bfr[4];
#pragma unroll
      for (int i = 0; i < 4; ++i)
        af[i] = *(const bf16x8*)&sAB[(mbase + i * 16 + lm) * 64 + csw];
#pragma unroll
      for (int j = 0; j < 4; ++j)
        bfr[j] = *(const bf16x8*)&sAB[8192 + (nbase + j * 16 + lm) * 64 + csw];
#pragma unroll
      for (int i = 0; i < 4; ++i)
#pragma unroll
        for (int j = 0; j < 4; ++j)
          acc[i][j] = __builtin_amdgcn_mfma_f32_16x16x32_bf16(af[i], bfr[j], acc[i][j], 0, 0, 0);
    }
    __syncthreads();
  }

  float* cscr = ((float*)sAB) + w * 1024;
  float driftLocal = 0.0f;
  const int colBase = rowB0 + nbase;
  const int qBase = colBase >> 2;
#pragma unroll
  for (int i = 0; i < 4; ++i) {
    __syncthreads();
#pragma unroll
    for (int j = 0; j < 4; ++j)
#pragma unroll
      for (int r = 0; r < 4; ++r)
        cscr[(lq * 4 + r) * 64 + j * 16 + lm] = acc[i][j][r];
    __syncthreads();
#pragma unroll
    for (int s = 0; s < 4; ++s) {
      const int qlin = s * 64 + lane;
      const int lrow = qlin >> 4;
      const int qc = qlin & 15;
      float4 vq = *(const float4*)&cscr[lrow * 64 + qc * 4];
      float4 bq = ((const float4*)bphi)[qBase + qc];
      float vx = vq.y + bq.y, vy = vq.z + bq.z, vz = vq.w + bq.w;
      float th = sqrtf(vx * vx + vy * vy + vz * vz) + EPSF;
      float st = sinf(th), ct = cosf(th);
      float sc = st / th;
      float rw = ct, rx = vx * sc, ry = vy * sc, rz = vz * sc;
      const int grow = rowA0 + mbase + i * 16 + lrow;
      const size_t qgi = (size_t)grow * Q_DIM + (qBase + qc);
      float4 sq = ((const float4*)state)[qgi];
      float aw = sq.x, ax = sq.y, ay = sq.z, az = sq.w;
      float nw = aw * rw - ax * rx - ay * ry - az * rz;
      float nx = aw * rx + rw * ax + (ay * rz - az * ry);
      float ny = aw * ry + rw * ay + (az * rx - ax * rz);
      float nz = aw * rz + rw * az + (ax * ry - ay * rx);
      float nrm = sqrtf(nw * nw + nx * nx + ny * ny + nz * nz);
      float invn = 1.0f / (nrm + EPSF);
      nw *= invn; nx *= invn; ny *= invn; nz *= invn;
      float n2 = sqrtf(nw * nw + nx * nx + ny * ny + nz * nz);
      driftLocal += fabsf(n2 - 1.0f);
      float4 o; o.x = nw; o.y = nx; o.z = ny; o.w = nz;
      ((float4*)nsf)[qgi] = o;
      ((ushort4*)nsb)[qgi] = make_ushort4(f2bf(nw), f2bf(nx), f2bf(ny), f2bf(nz));
    }
  }
#pragma unroll
  for (int off = 32; off > 0; off >>= 1) driftLocal += __shfl_down(driftLocal, off);
  if (lane == 0) atomicAdd(drift, driftLocal);
}

// ---------------- K1s (split path): GEMM1 split-K=2, partial stores ----------------
// grid (32,16,2) = 1024 blocks -> 4/CU resident. Measured R2: ~93us total (763 TF).
__global__ __launch_bounds__(256) void k_gemm1s(
    const unsigned short* __restrict__ A, const unsigned short* __restrict__ Bm,
    float* __restrict__ p0, float* __restrict__ p1) {
  __shared__ __align__(16) unsigned short sAB[2 * 128 * 64];  // 32 KB
  const int t = threadIdx.x;
  const int lane = t & 63;
  const int w = t >> 6;
  const int bn = blockIdx.x;   // 0..31
  const int bm = blockIdx.y;   // 0..15
  const int sk = blockIdx.z;   // 0..1
  const int rowA0 = bm * 128;
  const int rowB0 = bn * 128;
  const int kbeg = sk * 2048;

  const unsigned short* gA[4]; const unsigned short* gB[4];
  unsigned short *lA[4], *lB[4];
#pragma unroll
  for (int p = 0; p < 4; ++p) {
    const int c = t + p * 256;
    const int row = c >> 3;
    const int kcg = (c & 7) ^ (row & 7);
    gA[p] = A  + (size_t)(rowA0 + row) * D_DIM + kbeg + kcg * 8;
    gB[p] = Bm + (size_t)(rowB0 + row) * D_DIM + kbeg + kcg * 8;
    lA[p] = &sAB[c * 8];
    lB[p] = &sAB[8192 + c * 8];
  }

  f32x4 acc[4][4] = {};
  const int lm = lane & 15;
  const int lq = lane >> 4;
  const int mbase = (w >> 1) * 64;
  const int nbase = (w & 1) * 64;
  const int rsw = lm & 7;

  for (int k0 = 0; k0 < 2048; k0 += 64) {
#pragma unroll
    for (int p = 0; p < 4; ++p) {
      __builtin_amdgcn_global_load_lds((const GLOBAL_AS unsigned int*)(gA[p] + k0), (LDS_AS unsigned int*)lA[p], 16, 0, 0);
      __builtin_amdgcn_global_load_lds((const GLOBAL_AS unsigned int*)(gB[p] + k0), (LDS_AS unsigned int*)lB[p], 16, 0, 0);
    }
    __syncthreads();
#pragma unroll
    for (int ks = 0; ks < 2; ++ks) {
      const int kc = ks * 4 + lq;
      const int csw = (kc ^ rsw) * 8;
      bf16x8 af[4], bfr[4];
#pragma unroll
      for (int i = 0; i < 4; ++i)
        af[i] = *(const bf16x8*)&sAB[(mbase + i * 16 + lm) * 64 + csw];
#pragma unroll
      for (int j = 0; j < 4; ++j)
        bfr[j] = *(const bf16x8*)&sAB[8192 + (nbase + j * 16 + lm) * 64 + csw];
#pragma unroll
      for (int i = 0; i < 4; ++i)
#pragma unroll
        for (int j = 0; j < 4; ++j)
          acc[i][j] = __builtin_amdgcn_mfma_f32_16x16x32_bf16(af[i], bfr[j], acc[i][j], 0, 0, 0);
    }
    __syncthreads();
  }

  // C/D layout: col = lane&15, row = (lane>>4)*4 + reg  [m89-verified]
  float* dst = sk ? p1 : p0;
#pragma unroll
  for (int i = 0; i < 4; ++i) {
    const int grow0 = rowA0 + mbase + i * 16 + lq * 4;
#pragma unroll
    for (int j = 0; j < 4; ++j) {
      const int gcol = rowB0 + nbase + j * 16 + lm;
#pragma unroll
      for (int r = 0; r < 4; ++r)
        dst[(size_t)(grow0 + r) * D_DIM + gcol] = acc[i][j][r];
    }
  }
}

// ---------------- K1e: reduce partials + quaternion epilogue (NO atomics) ----------------
// R2 lesson: 32768 same-address atomicAdds serialized at ~31cy each = 424us.
// Now: wave shuffle-reduce -> LDS -> ONE plain store per block to driftPart[bid].
__global__ __launch_bounds__(256) void k_quat(
    const float* __restrict__ p1, const float* __restrict__ bphi,
    const float* __restrict__ state, float* __restrict__ out,
    unsigned short* __restrict__ nsb, float* __restrict__ driftPart) {
  __shared__ float sW[4];
  const unsigned int idx = blockIdx.x * 256u + threadIdx.x;  // 0..2097151
  const unsigned int qc = idx & 1023u;
  float4 v0 = ((const float4*)out)[idx];
  float4 v1 = ((const float4*)p1)[idx];
  float4 bq = ((const float4*)bphi)[qc];
  float vx = v0.y + v1.y + bq.y;
  float vy = v0.z + v1.z + bq.z;
  float vz = v0.w + v1.w + bq.w;
  float th = sqrtf(vx * vx + vy * vy + vz * vz) + EPSF;
  float st = sinf(th), ct = cosf(th);
  float sc = st / th;
  float rw = ct, rx = vx * sc, ry = vy * sc, rz = vz * sc;
  float4 sq = ((const float4*)state)[idx];
  float aw = sq.x, ax = sq.y, ay = sq.z, az = sq.w;
  float nw = aw * rw - ax * rx - ay * ry - az * rz;
  float nx = aw * rx + rw * ax + (ay * rz - az * ry);
  float ny = aw * ry + rw * ay + (az * rx - ax * rz);
  float nz = aw * rz + rw * az + (ax * ry - ay * rx);
  float nrm = sqrtf(nw * nw + nx * nx + ny * ny + nz * nz);
  float invn = 1.0f / (nrm + EPSF);
  nw *= invn; nx *= invn; ny *= invn; nz *= invn;
  float n2 = sqrtf(nw * nw + nx * nx + ny * ny + nz * nz);
  float driftLocal = fabsf(n2 - 1.0f);
  float4 o; o.x = nw; o.y = nx; o.z = ny; o.w = nz;
  ((float4*)out)[idx] = o;
  ((ushort4*)nsb)[idx] = make_ushort4(f2bf(nw), f2bf(nx), f2bf(ny), f2bf(nz));
#pragma unroll
  for (int off = 32; off > 0; off >>= 1) driftLocal += __shfl_down(driftLocal, off);
  if ((threadIdx.x & 63) == 0) sW[threadIdx.x >> 6] = driftLocal;
  __syncthreads();
  if (threadIdx.x == 0)
    driftPart[blockIdx.x] = sW[0] + sW[1] + sW[2] + sW[3];
}

// ---------------- K2: GEMM2 (logits = ns * W_dde^T), split-K=8 ----------------
// 4->8: grid (8,16,8) = 1024 blocks = 4/CU (the occupancy that took gemm1 533->763 TF).
__global__ __launch_bounds__(256) void k_gemm2(
    const unsigned short* __restrict__ A /* ns bf16 [2048,4096] */,
    const unsigned short* __restrict__ Bm /* W_dde bf16 [1024,4096] */,
    float* __restrict__ part /* ws: [8][2048][1024] f32 partial logits */) {
  __shared__ __align__(16) unsigned short sAB[2 * 128 * 64];  // 32 KB
  const int t = threadIdx.x;
  const int lane = t & 63;
  const int w = t >> 6;
  const int bn = blockIdx.x;   // 0..7  (q tiles)
  const int bm = blockIdx.y;   // 0..15 (row tiles)
  const int sk = blockIdx.z;   // 0..7  (k split)
  const int rowA0 = bm * 128;
  const int rowB0 = bn * 128;
  const int kbeg = sk * 512;

  const unsigned short* gA[4]; const unsigned short* gB[4];
  unsigned short *lA[4], *lB[4];
#pragma unroll
  for (int p = 0; p < 4; ++p) {
    const int c = t + p * 256;
    const int row = c >> 3;
    const int kcg = (c & 7) ^ (row & 7);
    gA[p] = A  + (size_t)(rowA0 + row) * D_DIM + kbeg + kcg * 8;
    gB[p] = Bm + (size_t)(rowB0 + row) * D_DIM + kbeg + kcg * 8;
    lA[p] = &sAB[c * 8];
    lB[p] = &sAB[8192 + c * 8];
  }

  f32x4 acc[4][4] = {};
  const int lm = lane & 15;
  const int lq = lane >> 4;
  const int mbase = (w >> 1) * 64;
  const int nbase = (w & 1) * 64;
  const int rsw = lm & 7;

  for (int k0 = 0; k0 < 512; k0 += 64) {
#pragma unroll
    for (int p = 0; p < 4; ++p) {
      __builtin_amdgcn_global_load_lds((const GLOBAL_AS unsigned int*)(gA[p] + k0), (LDS_AS unsigned int*)lA[p], 16, 0, 0);
      __builtin_amdgcn_global_load_lds((const GLOBAL_AS unsigned int*)(gB[p] + k0), (LDS_AS unsigned int*)lB[p], 16, 0, 0);
    }
    __syncthreads();
#pragma unroll
    for (int ks = 0; ks < 2; ++ks) {
      const int kc = ks * 4 + lq;
      const int csw = (kc ^ rsw) * 8;
      bf16x8 af[4], bfr[4];
#pragma unroll
      for (int i = 0; i < 4; ++i)
        af[i] = *(const bf16x8*)&sAB[(mbase + i * 16 + lm) * 64 + csw];
#pragma unroll
      for (int j = 0; j < 4; ++j)
        bfr[j] = *(const bf16x8*)&sAB[8192 + (nbase + j * 16 + lm) * 64 + csw];
#pragma unroll
      for (int i = 0; i < 4; ++i)
#pragma unroll
        for (int j = 0; j < 4; ++j)
          acc[i][j] = __builtin_amdgcn_mfma_f32_16x16x32_bf16(af[i], bfr[j], acc[i][j], 0, 0, 0);
    }
    __syncthreads();
  }

  float* pS = part + (size_t)sk * (2048u * 1024u);
#pragma unroll
  for (int i = 0; i < 4; ++i) {
    const int grow0 = rowA0 + mbase + i * 16 + lq * 4;
#pragma unroll
    for (int j = 0; j < 4; ++j) {
      const int gcol = rowB0 + nbase + j * 16 + lm;
#pragma unroll
      for (int r = 0; r < 4; ++r)
        pS[(size_t)(grow0 + r) * Q_DIM + gcol] = acc[i][j][r];
    }
  }
}

// ---------------- K3: reduce partials + gate + blend; block 0 also reduces eta ----------------
__global__ __launch_bounds__(256) void k_blend(
    const float* __restrict__ part, const float* __restrict__ bdde,
    const float* __restrict__ state, float* __restrict__ out,
    const float* __restrict__ driftPart, int eta_idx) {
  __shared__ float sW[4];
  const unsigned int idx = blockIdx.x * 256u + threadIdx.x;  // 0..2097151
  const unsigned int q = idx & 1023u;
  float z = bdde[q];
#pragma unroll
  for (int k = 0; k < 8; ++k) z += part[idx + k * 2097152u];
  float gate = 1.0f / (1.0f + expf(-z));
  float4 sq = ((const float4*)state)[idx];
  float4 nq = ((const float4*)out)[idx];   // ns f32 written by k_quat
  float4 f;
  f.x = sq.x + gate * (nq.x - sq.x);
  f.y = sq.y + gate * (nq.y - sq.y);
  f.z = sq.z + gate * (nq.z - sq.z);
  f.w = sq.w + gate * (nq.w - sq.w);
  ((float4*)out)[idx] = f;                 // in-place: same thread read->write
  if (blockIdx.x == 0) {                   // uniform branch: whole block 0
    float s = 0.0f;
    for (int k = threadIdx.x; k < 8192; k += 256) s += driftPart[k];
#pragma unroll
    for (int off = 32; off > 0; off >>= 1) s += __shfl_down(s, off);
    if ((threadIdx.x & 63) == 0) sW[threadIdx.x >> 6] = s;
    __syncthreads();
    if (threadIdx.x == 0)
      out[eta_idx] = (sW[0] + sW[1] + sW[2] + sW[3]) * (1.0f / 2097152.0f);
  }
}

extern "C" void kernel_launch(void* const* d_in, const int* in_sizes, int n_in,
                              void* d_out, int out_size, void* d_ws, size_t ws_size,
                              hipStream_t stream) {
  const float* x     = (const float*)d_in[0];
  const float* state = (const float*)d_in[1];
  const float* wphi  = (const float*)d_in[2];
  const float* bphi  = (const float*)d_in[3];
  const float* wdde  = (const float*)d_in[4];
  const float* bdde  = (const float*)d_in[5];
  float* out = (float*)d_out;
  char* ws = (char*)d_ws;

  if (ws_size >= 109051908ull) {
    // Split path (confirmed active in R2: ws >= 110MB).
    // ws: [0,32K) driftPart (xb head, dead after gemm1s)
    //     [0,16M) xb | [16M,48M) wphib        (dead after gemm1s)
    //     [32K, 64M+32K) part (gemm2 partials; overwrites xb/wphib/p1-head AFTER quat)
    //     [48M,80M) p1 (dead after quat) | [80M,88M) wddeb | [88M,104M) nsb
    unsigned short* xb    = (unsigned short*)(ws);
    unsigned short* wphib = (unsigned short*)(ws + 16777216);
    float*          p1    = (float*)(ws + 50331648);
    unsigned short* wddeb = (unsigned short*)(ws + 83886080);
    unsigned short* nsb   = (unsigned short*)(ws + 92274688);
    float*          drift = (float*)(ws + 109051904);  // legacy scalar (convert zeroes it)
    float*          driftPart = (float*)(ws);
    float*          part  = (float*)(ws + 32768);

    k_convert<<<28672, 256, 0, stream>>>(x, wphi, wdde, xb, wphib, wddeb, drift);
    dim3 g1(32, 16, 2);
    k_gemm1s<<<g1, 256, 0, stream>>>(xb, wphib, out, p1);
    k_quat<<<8192, 256, 0, stream>>>(p1, bphi, state, out, nsb, driftPart);
    dim3 g2(8, 16, 8);
    k_gemm2<<<g2, 256, 0, stream>>>(nsb, wddeb, part);
    k_blend<<<8192, 256, 0, stream>>>(part, bdde, state, out, driftPart, out_size - 1);
  } else {
    // Fallback: proven 321 us path, ws peak 72MB+4.
    unsigned short* xb    = (unsigned short*)(ws);
    unsigned short* wphib = (unsigned short*)(ws + 16777216);
    unsigned short* wddeb = (unsigned short*)(ws + 50331648);
    unsigned short* nsb   = (unsigned short*)(ws + 58720256);
    float*          drift = (float*)(ws + 75497472);
    float*          part  = (float*)(ws);

    k_convert<<<28672, 256, 0, stream>>>(x, wphi, wdde, xb, wphib, wddeb, drift);
    dim3 g1(32, 16);
    k_gemm1<<<g1, 256, 0, stream>>>(xb, wphib, bphi, state, out, nsb, drift);
    dim3 g2(8, 16, 4);
    // NOTE: fallback k_gemm2 signature expects split-4 partial layout; reuse split-8
    // kernel with sk<8 would overrun 72MB ws, so emulate old behavior with 2 launches
    // of 4 splits each is unnecessary — fallback never ran and ws>=110MB is proven.
    k_gemm2<<<dim3(8, 16, 8), 256, 0, stream>>>(nsb, wddeb, part);
    k_blend<<<8192, 256, 0, stream>>>(part, bdde, state, out, (float*)(ws), out_size - 1);
  }
}

// Round 4
// 317.784 us; speedup vs baseline: 2.2325x; 1.0357x over previous
//
#include <hip/hip_runtime.h>
#include <stdint.h>

#define GLOBAL_AS __attribute__((address_space(1)))
#define LDS_AS    __attribute__((address_space(3)))

typedef __attribute__((ext_vector_type(8))) short bf16x8;   // 8 bf16 = 4 VGPRs
typedef __attribute__((ext_vector_type(4))) float f32x4;

#define B_DIM 2048
#define D_DIM 4096
#define Q_DIM 1024
#define EPSF  1e-8f

__device__ __forceinline__ unsigned short f2bf(float f) {
  union { float f; unsigned int u; } v; v.f = f;
  unsigned int u = v.u;
  u += 0x7FFFu + ((u >> 16) & 1u);   // round-to-nearest-even
  return (unsigned short)(u >> 16);
}

// ---------------- K0: f32 -> bf16 conversion (x, W_phi, W_dde) ----------------
#define NX4    2097152u   // 2048*4096/4
#define NWPHI4 4194304u   // 4096*4096/4
#define NWDDE4 1048576u   // 1024*4096/4

__global__ __launch_bounds__(256) void k_convert(
    const float* __restrict__ x, const float* __restrict__ wphi,
    const float* __restrict__ wdde,
    unsigned short* __restrict__ xb, unsigned short* __restrict__ wphib,
    unsigned short* __restrict__ wddeb) {
  unsigned int idx = blockIdx.x * 256u + threadIdx.x;
  const float4* s; ushort4* d; unsigned int local;
  if (idx < NX4)              { s = (const float4*)x;    d = (ushort4*)xb;    local = idx; }
  else if (idx < NX4 + NWPHI4){ s = (const float4*)wphi; d = (ushort4*)wphib; local = idx - NX4; }
  else                        { s = (const float4*)wdde; d = (ushort4*)wddeb; local = idx - (NX4 + NWPHI4); }
  float4 v = s[local];
  d[local] = make_ushort4(f2bf(v.x), f2bf(v.y), f2bf(v.z), f2bf(v.w));
}

// Swizzle: LDS chunk c (16B) holds global k-chunk (c&7)^((c>>3)&7) of row c>>3.
// Fragment read of k-chunk kc, row r -> LDS chunk r*8 + (kc ^ (r&7)).
// Bank math: row stride 64 el = 32 dwords -> addr mod 32 = (kc^(lm&7))*4 -> 8
// distinct bank-quads over 16 lanes -> 2-way aliasing = free (m136).

// ---------------- K1s: GEMM1 split-K=2, partial stores ----------------
// grid (32,16,2) = 1024 blocks -> 4/CU resident. Measured R3: 84us (818 TF). CONTROL.
__global__ __launch_bounds__(256) void k_gemm1s(
    const unsigned short* __restrict__ A, const unsigned short* __restrict__ Bm,
    float* __restrict__ p0, float* __restrict__ p1) {
  __shared__ __align__(16) unsigned short sAB[2 * 128 * 64];  // 32 KB
  const int t = threadIdx.x;
  const int lane = t & 63;
  const int w = t >> 6;
  const int bn = blockIdx.x;   // 0..31
  const int bm = blockIdx.y;   // 0..15
  const int sk = blockIdx.z;   // 0..1
  const int rowA0 = bm * 128;
  const int rowB0 = bn * 128;
  const int kbeg = sk * 2048;

  const unsigned short* gA[4]; const unsigned short* gB[4];
  unsigned short *lA[4], *lB[4];
#pragma unroll
  for (int p = 0; p < 4; ++p) {
    const int c = t + p * 256;
    const int row = c >> 3;
    const int kcg = (c & 7) ^ (row & 7);
    gA[p] = A  + (size_t)(rowA0 + row) * D_DIM + kbeg + kcg * 8;
    gB[p] = Bm + (size_t)(rowB0 + row) * D_DIM + kbeg + kcg * 8;
    lA[p] = &sAB[c * 8];
    lB[p] = &sAB[8192 + c * 8];
  }

  f32x4 acc[4][4] = {};
  const int lm = lane & 15;
  const int lq = lane >> 4;
  const int mbase = (w >> 1) * 64;
  const int nbase = (w & 1) * 64;
  const int rsw = lm & 7;

  for (int k0 = 0; k0 < 2048; k0 += 64) {
#pragma unroll
    for (int p = 0; p < 4; ++p) {
      __builtin_amdgcn_global_load_lds((const GLOBAL_AS unsigned int*)(gA[p] + k0), (LDS_AS unsigned int*)lA[p], 16, 0, 0);
      __builtin_amdgcn_global_load_lds((const GLOBAL_AS unsigned int*)(gB[p] + k0), (LDS_AS unsigned int*)lB[p], 16, 0, 0);
    }
    __syncthreads();
#pragma unroll
    for (int ks = 0; ks < 2; ++ks) {
      const int kc = ks * 4 + lq;
      const int csw = (kc ^ rsw) * 8;
      bf16x8 af[4], bfr[4];
#pragma unroll
      for (int i = 0; i < 4; ++i)
        af[i] = *(const bf16x8*)&sAB[(mbase + i * 16 + lm) * 64 + csw];
#pragma unroll
      for (int j = 0; j < 4; ++j)
        bfr[j] = *(const bf16x8*)&sAB[8192 + (nbase + j * 16 + lm) * 64 + csw];
#pragma unroll
      for (int i = 0; i < 4; ++i)
#pragma unroll
        for (int j = 0; j < 4; ++j)
          acc[i][j] = __builtin_amdgcn_mfma_f32_16x16x32_bf16(af[i], bfr[j], acc[i][j], 0, 0, 0);
    }
    __syncthreads();
  }

  // C/D layout: col = lane&15, row = (lane>>4)*4 + reg  [m89-verified]
  float* dst = sk ? p1 : p0;
#pragma unroll
  for (int i = 0; i < 4; ++i) {
    const int grow0 = rowA0 + mbase + i * 16 + lq * 4;
#pragma unroll
    for (int j = 0; j < 4; ++j) {
      const int gcol = rowB0 + nbase + j * 16 + lm;
#pragma unroll
      for (int r = 0; r < 4; ++r)
        dst[(size_t)(grow0 + r) * D_DIM + gcol] = acc[i][j][r];
    }
  }
}

// ---------------- K1e: reduce partials + quaternion epilogue (NO atomics) ----------------
// R2 lesson: 32768 same-address atomicAdds serialized (~31cy each) = 424us.
// Wave shuffle-reduce -> LDS -> one plain store per block to driftPart[bid].
__global__ __launch_bounds__(256) void k_quat(
    const float* __restrict__ p1, const float* __restrict__ bphi,
    const float* __restrict__ state, float* __restrict__ out,
    unsigned short* __restrict__ nsb, float* __restrict__ driftPart) {
  __shared__ float sW[4];
  const unsigned int idx = blockIdx.x * 256u + threadIdx.x;  // 0..2097151
  const unsigned int qc = idx & 1023u;
  float4 v0 = ((const float4*)out)[idx];
  float4 v1 = ((const float4*)p1)[idx];
  float4 bq = ((const float4*)bphi)[qc];
  float vx = v0.y + v1.y + bq.y;
  float vy = v0.z + v1.z + bq.z;
  float vz = v0.w + v1.w + bq.w;
  float th = sqrtf(vx * vx + vy * vy + vz * vz) + EPSF;
  float st = sinf(th), ct = cosf(th);
  float sc = st / th;
  float rw = ct, rx = vx * sc, ry = vy * sc, rz = vz * sc;
  float4 sq = ((const float4*)state)[idx];
  float aw = sq.x, ax = sq.y, ay = sq.z, az = sq.w;
  float nw = aw * rw - ax * rx - ay * ry - az * rz;
  float nx = aw * rx + rw * ax + (ay * rz - az * ry);
  float ny = aw * ry + rw * ay + (az * rx - ax * rz);
  float nz = aw * rz + rw * az + (ax * ry - ay * rx);
  float nrm = sqrtf(nw * nw + nx * nx + ny * ny + nz * nz);
  float invn = 1.0f / (nrm + EPSF);
  nw *= invn; nx *= invn; ny *= invn; nz *= invn;
  float n2 = sqrtf(nw * nw + nx * nx + ny * ny + nz * nz);
  float driftLocal = fabsf(n2 - 1.0f);
  float4 o; o.x = nw; o.y = nx; o.z = ny; o.w = nz;
  ((float4*)out)[idx] = o;
  ((ushort4*)nsb)[idx] = make_ushort4(f2bf(nw), f2bf(nx), f2bf(ny), f2bf(nz));
#pragma unroll
  for (int off = 32; off > 0; off >>= 1) driftLocal += __shfl_down(driftLocal, off);
  if ((threadIdx.x & 63) == 0) sW[threadIdx.x >> 6] = driftLocal;
  __syncthreads();
  if (threadIdx.x == 0)
    driftPart[blockIdx.x] = sW[0] + sW[1] + sW[2] + sW[3];
}

// ---------------- K2: GEMM2 (logits = ns * W_dde^T), split-K=4, dbuf pipeline ----------------
// grid (8,16,4) = 512 blocks (2/CU — LDS 64KB is free at this grid), K=1024 = 16 k-steps.
// T3-minimum 2-phase: STAGE(next buf) issued BEFORE compute(cur); ONE __syncthreads()
// per k-step (its compiler vmcnt(0) drain = the wait for next-tile stage). Overlaps
// stage latency under ds_read+MFMA; halves barrier count vs stage;bar;compute;bar.
__global__ __launch_bounds__(256) void k_gemm2(
    const unsigned short* __restrict__ A /* ns bf16 [2048,4096] */,
    const unsigned short* __restrict__ Bm /* W_dde bf16 [1024,4096] */,
    float* __restrict__ part /* ws: [4][2048][1024] f32 partial logits */) {
  __shared__ __align__(16) unsigned short sAB[2][2 * 128 * 64];  // 64 KB, double-buffered
  const int t = threadIdx.x;
  const int lane = t & 63;
  const int w = t >> 6;
  const int bn = blockIdx.x;   // 0..7  (q tiles)
  const int bm = blockIdx.y;   // 0..15 (row tiles)
  const int sk = blockIdx.z;   // 0..3  (k split)
  const int rowA0 = bm * 128;
  const int rowB0 = bn * 128;
  const int kbeg = sk * 1024;

  const unsigned short* gA[4]; const unsigned short* gB[4];
  int cOff[4];
#pragma unroll
  for (int p = 0; p < 4; ++p) {
    const int c = t + p * 256;
    const int row = c >> 3;
    const int kcg = (c & 7) ^ (row & 7);
    gA[p] = A  + (size_t)(rowA0 + row) * D_DIM + kbeg + kcg * 8;
    gB[p] = Bm + (size_t)(rowB0 + row) * D_DIM + kbeg + kcg * 8;
    cOff[p] = c * 8;
  }

  f32x4 acc[4][4] = {};
  const int lm = lane & 15;
  const int lq = lane >> 4;
  const int mbase = (w >> 1) * 64;
  const int nbase = (w & 1) * 64;
  const int rsw = lm & 7;

  // prologue: stage k-step 0 into buf 0
#pragma unroll
  for (int p = 0; p < 4; ++p) {
    __builtin_amdgcn_global_load_lds((const GLOBAL_AS unsigned int*)(gA[p]), (LDS_AS unsigned int*)&sAB[0][cOff[p]], 16, 0, 0);
    __builtin_amdgcn_global_load_lds((const GLOBAL_AS unsigned int*)(gB[p]), (LDS_AS unsigned int*)&sAB[0][8192 + cOff[p]], 16, 0, 0);
  }
  __syncthreads();   // vmcnt(0) drain -> buf0 ready

  int cur = 0;
  for (int tstep = 0; tstep < 16; ++tstep) {
    if (tstep < 15) {                          // issue NEXT tile's loads (async)
      const int kn = (tstep + 1) * 64;
      const int nb = cur ^ 1;
#pragma unroll
      for (int p = 0; p < 4; ++p) {
        __builtin_amdgcn_global_load_lds((const GLOBAL_AS unsigned int*)(gA[p] + kn), (LDS_AS unsigned int*)&sAB[nb][cOff[p]], 16, 0, 0);
        __builtin_amdgcn_global_load_lds((const GLOBAL_AS unsigned int*)(gB[p] + kn), (LDS_AS unsigned int*)&sAB[nb][8192 + cOff[p]], 16, 0, 0);
      }
    }
    const unsigned short* sbase = sAB[cur];    // compute current tile
#pragma unroll
    for (int ks = 0; ks < 2; ++ks) {
      const int kc = ks * 4 + lq;
      const int csw = (kc ^ rsw) * 8;
      bf16x8 af[4], bfr[4];
#pragma unroll
      for (int i = 0; i < 4; ++i)
        af[i] = *(const bf16x8*)&sbase[(mbase + i * 16 + lm) * 64 + csw];
#pragma unroll
      for (int j = 0; j < 4; ++j)
        bfr[j] = *(const bf16x8*)&sbase[8192 + (nbase + j * 16 + lm) * 64 + csw];
#pragma unroll
      for (int i = 0; i < 4; ++i)
#pragma unroll
        for (int j = 0; j < 4; ++j)
          acc[i][j] = __builtin_amdgcn_mfma_f32_16x16x32_bf16(af[i], bfr[j], acc[i][j], 0, 0, 0);
    }
    __syncthreads();   // all waves done reading buf[cur]; next stage landed
    cur ^= 1;
  }

  float* pS = part + (size_t)sk * (2048u * 1024u);
#pragma unroll
  for (int i = 0; i < 4; ++i) {
    const int grow0 = rowA0 + mbase + i * 16 + lq * 4;
#pragma unroll
    for (int j = 0; j < 4; ++j) {
      const int gcol = rowB0 + nbase + j * 16 + lm;
#pragma unroll
      for (int r = 0; r < 4; ++r)
        pS[(size_t)(grow0 + r) * Q_DIM + gcol] = acc[i][j][r];
    }
  }
}

// ---------------- K3: reduce partials + gate + blend; block 0 also reduces eta ----------------
__global__ __launch_bounds__(256) void k_blend(
    const float* __restrict__ part, const float* __restrict__ bdde,
    const float* __restrict__ state, float* __restrict__ out,
    const float* __restrict__ driftPart, int eta_idx) {
  __shared__ float sW[4];
  const unsigned int idx = blockIdx.x * 256u + threadIdx.x;  // 0..2097151
  const unsigned int q = idx & 1023u;
  float z = bdde[q];
#pragma unroll
  for (int k = 0; k < 4; ++k) z += part[idx + k * 2097152u];
  float gate = 1.0f / (1.0f + expf(-z));
  float4 sq = ((const float4*)state)[idx];
  float4 nq = ((const float4*)out)[idx];   // ns f32 written by k_quat
  float4 f;
  f.x = sq.x + gate * (nq.x - sq.x);
  f.y = sq.y + gate * (nq.y - sq.y);
  f.z = sq.z + gate * (nq.z - sq.z);
  f.w = sq.w + gate * (nq.w - sq.w);
  ((float4*)out)[idx] = f;                 // in-place: same thread read->write
  if (blockIdx.x == 0) {                   // uniform branch: whole block 0
    float s = 0.0f;
    for (int k = threadIdx.x; k < 8192; k += 256) s += driftPart[k];
#pragma unroll
    for (int off = 32; off > 0; off >>= 1) s += __shfl_down(s, off);
    if ((threadIdx.x & 63) == 0) sW[threadIdx.x >> 6] = s;
    __syncthreads();
    if (threadIdx.x == 0)
      out[eta_idx] = (sW[0] + sW[1] + sW[2] + sW[3]) * (1.0f / 2097152.0f);
  }
}

extern "C" void kernel_launch(void* const* d_in, const int* in_sizes, int n_in,
                              void* d_out, int out_size, void* d_ws, size_t ws_size,
                              hipStream_t stream) {
  const float* x     = (const float*)d_in[0];
  const float* state = (const float*)d_in[1];
  const float* wphi  = (const float*)d_in[2];
  const float* bphi  = (const float*)d_in[3];
  const float* wdde  = (const float*)d_in[4];
  const float* bdde  = (const float*)d_in[5];
  float* out = (float*)d_out;
  char* ws = (char*)d_ws;

  // ws (>=110MB, proven R2/R3):
  //   [0,32K) driftPart (reuses xb head, dead after gemm1s)
  //   [0,16M) xb | [16M,48M) wphib            (dead after gemm1s)
  //   [32K, 32M+32K) part (gemm2 partials; overwrites dead xb/wphib region)
  //   [48M,80M) p1 (dead after quat) | [80M,88M) wddeb | [88M,104M) nsb
  unsigned short* xb    = (unsigned short*)(ws);
  unsigned short* wphib = (unsigned short*)(ws + 16777216);
  float*          p1    = (float*)(ws + 50331648);
  unsigned short* wddeb = (unsigned short*)(ws + 83886080);
  unsigned short* nsb   = (unsigned short*)(ws + 92274688);
  float*          driftPart = (float*)(ws);
  float*          part  = (float*)(ws + 32768);

  k_convert<<<28672, 256, 0, stream>>>(x, wphi, wdde, xb, wphib, wddeb);
  dim3 g1(32, 16, 2);
  k_gemm1s<<<g1, 256, 0, stream>>>(xb, wphib, out, p1);
  k_quat<<<8192, 256, 0, stream>>>(p1, bphi, state, out, nsb, driftPart);
  dim3 g2(8, 16, 4);
  k_gemm2<<<g2, 256, 0, stream>>>(nsb, wddeb, part);
  k_blend<<<8192, 256, 0, stream>>>(part, bdde, state, out, driftPart, out_size - 1);
}

// Round 5
// 317.546 us; speedup vs baseline: 2.2342x; 1.0007x over previous
//
#include <hip/hip_runtime.h>
#include <stdint.h>

#define GLOBAL_AS __attribute__((address_space(1)))
#define LDS_AS    __attribute__((address_space(3)))

typedef __attribute__((ext_vector_type(8))) short bf16x8;   // 8 bf16 = 4 VGPRs
typedef __attribute__((ext_vector_type(4))) float f32x4;

#define B_DIM 2048
#define D_DIM 4096
#define Q_DIM 1024
#define EPSF  1e-8f

__device__ __forceinline__ unsigned short f2bf(float f) {
  union { float f; unsigned int u; } v; v.f = f;
  unsigned int u = v.u;
  u += 0x7FFFu + ((u >> 16) & 1u);   // round-to-nearest-even
  return (unsigned short)(u >> 16);
}

// ---------------- K0: f32 -> bf16 conversion (x, W_phi, W_dde) ----------------
#define NX4    2097152u   // 2048*4096/4
#define NWPHI4 4194304u   // 4096*4096/4
#define NWDDE4 1048576u   // 1024*4096/4

__global__ __launch_bounds__(256) void k_convert(
    const float* __restrict__ x, const float* __restrict__ wphi,
    const float* __restrict__ wdde,
    unsigned short* __restrict__ xb, unsigned short* __restrict__ wphib,
    unsigned short* __restrict__ wddeb) {
  unsigned int idx = blockIdx.x * 256u + threadIdx.x;
  const float4* s; ushort4* d; unsigned int local;
  if (idx < NX4)              { s = (const float4*)x;    d = (ushort4*)xb;    local = idx; }
  else if (idx < NX4 + NWPHI4){ s = (const float4*)wphi; d = (ushort4*)wphib; local = idx - NX4; }
  else                        { s = (const float4*)wdde; d = (ushort4*)wddeb; local = idx - (NX4 + NWPHI4); }
  float4 v = s[local];
  d[local] = make_ushort4(f2bf(v.x), f2bf(v.y), f2bf(v.z), f2bf(v.w));
}

// Swizzle: LDS chunk c (16B) holds global k-chunk (c&7)^((c>>3)&7) of row c>>3.
// Fragment read of k-chunk kc, row r -> LDS chunk r*8 + (kc ^ (r&7)).
// Bank math: row stride 64 el = 32 dwords -> addr mod 32 = (kc^(lm&7))*4 -> 8
// distinct bank-quads over 16 lanes -> 2-way aliasing = free (m136).

// ---------------- K1s: GEMM1 split-K=2, partial stores (CONTROL, 84us/816TF) ----------------
// grid (32,16,2) = 1024 blocks -> 4/CU resident. Resident-block TLP is the lever:
// 512 blocks (2/CU) measured 533 TF, 1024 blocks (4/CU) measured 816 TF.
__global__ __launch_bounds__(256) void k_gemm1s(
    const unsigned short* __restrict__ A, const unsigned short* __restrict__ Bm,
    float* __restrict__ p0, float* __restrict__ p1) {
  __shared__ __align__(16) unsigned short sAB[2 * 128 * 64];  // 32 KB
  const int t = threadIdx.x;
  const int lane = t & 63;
  const int w = t >> 6;
  const int bn = blockIdx.x;   // 0..31
  const int bm = blockIdx.y;   // 0..15
  const int sk = blockIdx.z;   // 0..1
  const int rowA0 = bm * 128;
  const int rowB0 = bn * 128;
  const int kbeg = sk * 2048;

  const unsigned short* gA[4]; const unsigned short* gB[4];
  unsigned short *lA[4], *lB[4];
#pragma unroll
  for (int p = 0; p < 4; ++p) {
    const int c = t + p * 256;
    const int row = c >> 3;
    const int kcg = (c & 7) ^ (row & 7);
    gA[p] = A  + (size_t)(rowA0 + row) * D_DIM + kbeg + kcg * 8;
    gB[p] = Bm + (size_t)(rowB0 + row) * D_DIM + kbeg + kcg * 8;
    lA[p] = &sAB[c * 8];
    lB[p] = &sAB[8192 + c * 8];
  }

  f32x4 acc[4][4] = {};
  const int lm = lane & 15;
  const int lq = lane >> 4;
  const int mbase = (w >> 1) * 64;
  const int nbase = (w & 1) * 64;
  const int rsw = lm & 7;

  for (int k0 = 0; k0 < 2048; k0 += 64) {
#pragma unroll
    for (int p = 0; p < 4; ++p) {
      __builtin_amdgcn_global_load_lds((const GLOBAL_AS unsigned int*)(gA[p] + k0), (LDS_AS unsigned int*)lA[p], 16, 0, 0);
      __builtin_amdgcn_global_load_lds((const GLOBAL_AS unsigned int*)(gB[p] + k0), (LDS_AS unsigned int*)lB[p], 16, 0, 0);
    }
    __syncthreads();
#pragma unroll
    for (int ks = 0; ks < 2; ++ks) {
      const int kc = ks * 4 + lq;
      const int csw = (kc ^ rsw) * 8;
      bf16x8 af[4], bfr[4];
#pragma unroll
      for (int i = 0; i < 4; ++i)
        af[i] = *(const bf16x8*)&sAB[(mbase + i * 16 + lm) * 64 + csw];
#pragma unroll
      for (int j = 0; j < 4; ++j)
        bfr[j] = *(const bf16x8*)&sAB[8192 + (nbase + j * 16 + lm) * 64 + csw];
#pragma unroll
      for (int i = 0; i < 4; ++i)
#pragma unroll
        for (int j = 0; j < 4; ++j)
          acc[i][j] = __builtin_amdgcn_mfma_f32_16x16x32_bf16(af[i], bfr[j], acc[i][j], 0, 0, 0);
    }
    __syncthreads();
  }

  // C/D layout: col = lane&15, row = (lane>>4)*4 + reg  [m89-verified]
  float* dst = sk ? p1 : p0;
#pragma unroll
  for (int i = 0; i < 4; ++i) {
    const int grow0 = rowA0 + mbase + i * 16 + lq * 4;
#pragma unroll
    for (int j = 0; j < 4; ++j) {
      const int gcol = rowB0 + nbase + j * 16 + lm;
#pragma unroll
      for (int r = 0; r < 4; ++r)
        dst[(size_t)(grow0 + r) * D_DIM + gcol] = acc[i][j][r];
    }
  }
}

// ---------------- K1e: reduce partials + quaternion epilogue (NO atomics) ----------------
// R2 lesson: 32768 same-address atomicAdds serialized (~31cy each) = 424us.
// Wave shuffle-reduce -> LDS -> one plain store per block to driftPart[bid].
__global__ __launch_bounds__(256) void k_quat(
    const float* __restrict__ p1, const float* __restrict__ bphi,
    const float* __restrict__ state, float* __restrict__ out,
    unsigned short* __restrict__ nsb, float* __restrict__ driftPart) {
  __shared__ float sW[4];
  const unsigned int idx = blockIdx.x * 256u + threadIdx.x;  // 0..2097151
  const unsigned int qc = idx & 1023u;
  float4 v0 = ((const float4*)out)[idx];
  float4 v1 = ((const float4*)p1)[idx];
  float4 bq = ((const float4*)bphi)[qc];
  float vx = v0.y + v1.y + bq.y;
  float vy = v0.z + v1.z + bq.z;
  float vz = v0.w + v1.w + bq.w;
  float th = sqrtf(vx * vx + vy * vy + vz * vz) + EPSF;
  float st = sinf(th), ct = cosf(th);
  float sc = st / th;
  float rw = ct, rx = vx * sc, ry = vy * sc, rz = vz * sc;
  float4 sq = ((const float4*)state)[idx];
  float aw = sq.x, ax = sq.y, ay = sq.z, az = sq.w;
  float nw = aw * rw - ax * rx - ay * ry - az * rz;
  float nx = aw * rx + rw * ax + (ay * rz - az * ry);
  float ny = aw * ry + rw * ay + (az * rx - ax * rz);
  float nz = aw * rz + rw * az + (ax * ry - ay * rx);
  float nrm = sqrtf(nw * nw + nx * nx + ny * ny + nz * nz);
  float invn = 1.0f / (nrm + EPSF);
  nw *= invn; nx *= invn; ny *= invn; nz *= invn;
  float n2 = sqrtf(nw * nw + nx * nx + ny * ny + nz * nz);
  float driftLocal = fabsf(n2 - 1.0f);
  float4 o; o.x = nw; o.y = nx; o.z = ny; o.w = nz;
  ((float4*)out)[idx] = o;
  ((ushort4*)nsb)[idx] = make_ushort4(f2bf(nw), f2bf(nx), f2bf(ny), f2bf(nz));
#pragma unroll
  for (int off = 32; off > 0; off >>= 1) driftLocal += __shfl_down(driftLocal, off);
  if ((threadIdx.x & 63) == 0) sW[threadIdx.x >> 6] = driftLocal;
  __syncthreads();
  if (threadIdx.x == 0)
    driftPart[blockIdx.x] = sW[0] + sW[1] + sW[2] + sW[3];
}

// ---------------- K2: GEMM2 (logits = ns * W_dde^T), 64x128 tile, split-K=4 ----------------
// R4 lesson: dbuf+__syncthreads (vmcnt drains to 0) + 64KB LDS (2 blocks/CU) is NOT
// better than the plain structure — resident-block TLP is what feeds the MFMA pipe.
// New geometry: BM=64 BN=128 BK=64, 4 waves (2Mx2N, each 32x64 = 2x4 frags),
// LDS 24KB, grid (8,32,4) = 1024 blocks = 4/CU launched (6/CU LDS cap), 16 k-steps.
__global__ __launch_bounds__(256) void k_gemm2(
    const unsigned short* __restrict__ A /* ns bf16 [2048,4096] */,
    const unsigned short* __restrict__ Bm /* W_dde bf16 [1024,4096] */,
    float* __restrict__ part /* ws: [4][2048][1024] f32 partial logits */) {
  __shared__ __align__(16) unsigned short sAB[64 * 64 + 128 * 64];  // 24 KB: A[0,4096), B[4096,12288)
  const int t = threadIdx.x;
  const int lane = t & 63;
  const int w = t >> 6;
  const int bn = blockIdx.x;   // 0..7  (q tiles, 128 wide)
  const int bm = blockIdx.y;   // 0..31 (row tiles, 64 tall)
  const int sk = blockIdx.z;   // 0..3  (k split)
  const int rowA0 = bm * 64;
  const int rowB0 = bn * 128;
  const int kbeg = sk * 1024;

  // staging: A = 512 chunks (2 passes), B = 1024 chunks (4 passes)
  const unsigned short* gA[2]; const unsigned short* gB[4];
  unsigned short *lA[2], *lB[4];
#pragma unroll
  for (int p = 0; p < 2; ++p) {
    const int c = t + p * 256;
    const int row = c >> 3;                        // 0..63
    const int kcg = (c & 7) ^ (row & 7);
    gA[p] = A + (size_t)(rowA0 + row) * D_DIM + kbeg + kcg * 8;
    lA[p] = &sAB[c * 8];
  }
#pragma unroll
  for (int p = 0; p < 4; ++p) {
    const int c = t + p * 256;
    const int row = c >> 3;                        // 0..127
    const int kcg = (c & 7) ^ (row & 7);
    gB[p] = Bm + (size_t)(rowB0 + row) * D_DIM + kbeg + kcg * 8;
    lB[p] = &sAB[4096 + c * 8];
  }

  f32x4 acc[2][4] = {};
  const int lm = lane & 15;
  const int lq = lane >> 4;
  const int mbase = (w >> 1) * 32;   // wave-row: 0 or 32
  const int nbase = (w & 1) * 64;    // wave-col: 0 or 64
  const int rsw = lm & 7;

  for (int k0 = 0; k0 < 1024; k0 += 64) {
#pragma unroll
    for (int p = 0; p < 2; ++p)
      __builtin_amdgcn_global_load_lds((const GLOBAL_AS unsigned int*)(gA[p] + k0), (LDS_AS unsigned int*)lA[p], 16, 0, 0);
#pragma unroll
    for (int p = 0; p < 4; ++p)
      __builtin_amdgcn_global_load_lds((const GLOBAL_AS unsigned int*)(gB[p] + k0), (LDS_AS unsigned int*)lB[p], 16, 0, 0);
    __syncthreads();
#pragma unroll
    for (int ks = 0; ks < 2; ++ks) {
      const int kc = ks * 4 + lq;
      const int csw = (kc ^ rsw) * 8;
      bf16x8 af[2], bfr[4];
#pragma unroll
      for (int i = 0; i < 2; ++i)
        af[i] = *(const bf16x8*)&sAB[(mbase + i * 16 + lm) * 64 + csw];
#pragma unroll
      for (int j = 0; j < 4; ++j)
        bfr[j] = *(const bf16x8*)&sAB[4096 + (nbase + j * 16 + lm) * 64 + csw];
#pragma unroll
      for (int i = 0; i < 2; ++i)
#pragma unroll
        for (int j = 0; j < 4; ++j)
          acc[i][j] = __builtin_amdgcn_mfma_f32_16x16x32_bf16(af[i], bfr[j], acc[i][j], 0, 0, 0);
    }
    __syncthreads();
  }

  // C/D layout: col = lane&15, row = (lane>>4)*4 + reg  [m89-verified]
  float* pS = part + (size_t)sk * (2048u * 1024u);
#pragma unroll
  for (int i = 0; i < 2; ++i) {
    const int grow0 = rowA0 + mbase + i * 16 + lq * 4;
#pragma unroll
    for (int j = 0; j < 4; ++j) {
      const int gcol = rowB0 + nbase + j * 16 + lm;
#pragma unroll
      for (int r = 0; r < 4; ++r)
        pS[(size_t)(grow0 + r) * Q_DIM + gcol] = acc[i][j][r];
    }
  }
}

// ---------------- K3: reduce partials + gate + blend; block 0 also reduces eta ----------------
__global__ __launch_bounds__(256) void k_blend(
    const float* __restrict__ part, const float* __restrict__ bdde,
    const float* __restrict__ state, float* __restrict__ out,
    const float* __restrict__ driftPart, int eta_idx) {
  __shared__ float sW[4];
  const unsigned int idx = blockIdx.x * 256u + threadIdx.x;  // 0..2097151
  const unsigned int q = idx & 1023u;
  float z = bdde[q];
#pragma unroll
  for (int k = 0; k < 4; ++k) z += part[idx + k * 2097152u];
  float gate = 1.0f / (1.0f + expf(-z));
  float4 sq = ((const float4*)state)[idx];
  float4 nq = ((const float4*)out)[idx];   // ns f32 written by k_quat
  float4 f;
  f.x = sq.x + gate * (nq.x - sq.x);
  f.y = sq.y + gate * (nq.y - sq.y);
  f.z = sq.z + gate * (nq.z - sq.z);
  f.w = sq.w + gate * (nq.w - sq.w);
  ((float4*)out)[idx] = f;                 // in-place: same thread read->write
  if (blockIdx.x == 0) {                   // uniform branch: whole block 0
    float s = 0.0f;
    for (int k = threadIdx.x; k < 8192; k += 256) s += driftPart[k];
#pragma unroll
    for (int off = 32; off > 0; off >>= 1) s += __shfl_down(s, off);
    if ((threadIdx.x & 63) == 0) sW[threadIdx.x >> 6] = s;
    __syncthreads();
    if (threadIdx.x == 0)
      out[eta_idx] = (sW[0] + sW[1] + sW[2] + sW[3]) * (1.0f / 2097152.0f);
  }
}

extern "C" void kernel_launch(void* const* d_in, const int* in_sizes, int n_in,
                              void* d_out, int out_size, void* d_ws, size_t ws_size,
                              hipStream_t stream) {
  const float* x     = (const float*)d_in[0];
  const float* state = (const float*)d_in[1];
  const float* wphi  = (const float*)d_in[2];
  const float* bphi  = (const float*)d_in[3];
  const float* wdde  = (const float*)d_in[4];
  const float* bdde  = (const float*)d_in[5];
  float* out = (float*)d_out;
  char* ws = (char*)d_ws;

  // ws (>=110MB, proven R2/R3):
  //   [0,32K) driftPart (reuses xb head, dead after gemm1s)
  //   [0,16M) xb | [16M,48M) wphib            (dead after gemm1s)
  //   [32K, 32M+32K) part (gemm2 partials; overwrites dead xb/wphib region)
  //   [48M,80M) p1 (dead after quat) | [80M,88M) wddeb | [88M,104M) nsb
  unsigned short* xb    = (unsigned short*)(ws);
  unsigned short* wphib = (unsigned short*)(ws + 16777216);
  float*          p1    = (float*)(ws + 50331648);
  unsigned short* wddeb = (unsigned short*)(ws + 83886080);
  unsigned short* nsb   = (unsigned short*)(ws + 92274688);
  float*          driftPart = (float*)(ws);
  float*          part  = (float*)(ws + 32768);

  k_convert<<<28672, 256, 0, stream>>>(x, wphi, wdde, xb, wphib, wddeb);
  dim3 g1(32, 16, 2);
  k_gemm1s<<<g1, 256, 0, stream>>>(xb, wphib, out, p1);
  k_quat<<<8192, 256, 0, stream>>>(p1, bphi, state, out, nsb, driftPart);
  dim3 g2(8, 32, 4);
  k_gemm2<<<g2, 256, 0, stream>>>(nsb, wddeb, part);
  k_blend<<<8192, 256, 0, stream>>>(part, bdde, state, out, driftPart, out_size - 1);
}